// Round 5
// baseline (875.104 us; speedup 1.0000x reference)
//
#include <hip/hip_runtime.h>

#define NN 50000
#define NE 800000
#define FF 128
#define KF 8
#define DD 16
#define GG 512
#define BN_EPS 1e-5f
#define NB 196  // ceil(NN/256)

// ---------------- CSR build ----------------
__global__ void k_deg(const int* __restrict__ dst, int* __restrict__ deg) {
    int e = blockIdx.x * 256 + threadIdx.x;
    if (e < NE) atomicAdd(&deg[dst[e]], 1);
}

__global__ __launch_bounds__(256) void k_bsum(const int* __restrict__ deg, int* __restrict__ bsum) {
    int idx = blockIdx.x * 256 + threadIdx.x;
    int v = (idx < NN) ? deg[idx] : 0;
#pragma unroll
    for (int off = 32; off; off >>= 1) v += __shfl_down(v, off, 64);
    __shared__ int ws[4];
    if ((threadIdx.x & 63) == 0) ws[threadIdx.x >> 6] = v;
    __syncthreads();
    if (threadIdx.x == 0) bsum[blockIdx.x] = ws[0] + ws[1] + ws[2] + ws[3];
}

__global__ __launch_bounds__(256) void k_bscan(const int* __restrict__ bsum, int* __restrict__ boffs) {
    __shared__ int s[256];
    int tid = threadIdx.x;
    int v = (tid < NB) ? bsum[tid] : 0;
    s[tid] = v;
    __syncthreads();
    for (int off = 1; off < 256; off <<= 1) {
        int t = (tid >= off) ? s[tid - off] : 0;
        __syncthreads();
        s[tid] += t;
        __syncthreads();
    }
    if (tid < NB) boffs[tid] = s[tid] - v;  // exclusive
}

__global__ __launch_bounds__(256) void k_offs(const int* __restrict__ deg,
                                              const int* __restrict__ boffs,
                                              int* __restrict__ offs) {
    __shared__ int s[256];
    int tid = threadIdx.x;
    int idx = blockIdx.x * 256 + tid;
    int v = (idx < NN) ? deg[idx] : 0;
    s[tid] = v;
    __syncthreads();
    for (int off = 1; off < 256; off <<= 1) {
        int t = (tid >= off) ? s[tid - off] : 0;
        __syncthreads();
        s[tid] += t;
        __syncthreads();
    }
    int incl = s[tid];
    if (idx < NN) offs[idx] = boffs[blockIdx.x] + incl - v;
    if (idx == NN - 1) offs[NN] = boffs[blockIdx.x] + incl;
}

__global__ void k_fill(const int* __restrict__ src, const int* __restrict__ dst,
                       const int* __restrict__ offs, int* __restrict__ cnt,
                       int* __restrict__ csr) {
    int e = blockIdx.x * 256 + threadIdx.x;
    if (e < NE) {
        int d = dst[e];
        int p = atomicAdd(&cnt[d], 1);
        csr[offs[d] + p] = src[e];
    }
}

// ---------------- aggregation with fused (optional) BN affine (+relu) on load ------
// R3-proven config: unroll 8, ~32 VGPR, occ ~65% — at the gather-plateau (~3.6 TB/s L3)
template <bool BN, bool RELU>
__global__ __launch_bounds__(256) void k_agg(const float4* __restrict__ X,
                                             const int* __restrict__ offs,
                                             const int* __restrict__ csr,
                                             const float* __restrict__ st,
                                             const float* __restrict__ g,
                                             const float* __restrict__ be,
                                             float4* __restrict__ Z) {
    int grp = threadIdx.x >> 5;
    int lane = threadIdx.x & 31;
    int n = blockIdx.x * 8 + grp;

    float4 a4 = make_float4(1.f, 1.f, 1.f, 1.f);
    float4 b4 = make_float4(0.f, 0.f, 0.f, 0.f);
    if (BN) {
        const float inv_n = 1.0f / (float)NN;
        float av[4], bv[4];
#pragma unroll
        for (int t = 0; t < 4; t++) {
            int c = lane * 4 + t;
            float mu = st[c] * inv_n;
            float var = st[FF + c] * inv_n - mu * mu;
            float a = g[c] * rsqrtf(var + BN_EPS);
            av[t] = a;
            bv[t] = be[c] - mu * a;
        }
        a4 = make_float4(av[0], av[1], av[2], av[3]);
        b4 = make_float4(bv[0], bv[1], bv[2], bv[3]);
    }

    auto apply = [&](float4 v) -> float4 {
        if (BN) {
            v.x = fmaf(v.x, a4.x, b4.x);
            v.y = fmaf(v.y, a4.y, b4.y);
            v.z = fmaf(v.z, a4.z, b4.z);
            v.w = fmaf(v.w, a4.w, b4.w);
        }
        if (RELU) {
            v.x = fmaxf(v.x, 0.f);
            v.y = fmaxf(v.y, 0.f);
            v.z = fmaxf(v.z, 0.f);
            v.w = fmaxf(v.w, 0.f);
        }
        return v;
    };
    auto add4 = [](float4& a, float4 b) {
        a.x += b.x; a.y += b.y; a.z += b.z; a.w += b.w;
    };

    float4 acc = apply(X[(size_t)n * 32 + lane]);
    int e0 = offs[n], e1 = offs[n + 1];
    int e = e0;
    for (; e + 8 <= e1; e += 8) {
        int s0 = csr[e], s1 = csr[e + 1], s2 = csr[e + 2], s3 = csr[e + 3];
        int s4 = csr[e + 4], s5 = csr[e + 5], s6 = csr[e + 6], s7 = csr[e + 7];
        float4 v0 = X[(size_t)s0 * 32 + lane];
        float4 v1 = X[(size_t)s1 * 32 + lane];
        float4 v2 = X[(size_t)s2 * 32 + lane];
        float4 v3 = X[(size_t)s3 * 32 + lane];
        float4 v4 = X[(size_t)s4 * 32 + lane];
        float4 v5 = X[(size_t)s5 * 32 + lane];
        float4 v6 = X[(size_t)s6 * 32 + lane];
        float4 v7 = X[(size_t)s7 * 32 + lane];
        v0 = apply(v0); v1 = apply(v1); v2 = apply(v2); v3 = apply(v3);
        v4 = apply(v4); v5 = apply(v5); v6 = apply(v6); v7 = apply(v7);
        add4(v0, v1); add4(v2, v3); add4(v4, v5); add4(v6, v7);
        add4(v0, v2); add4(v4, v6); add4(v0, v4); add4(acc, v0);
    }
    for (; e + 4 <= e1; e += 4) {
        int s0 = csr[e], s1 = csr[e + 1], s2 = csr[e + 2], s3 = csr[e + 3];
        float4 v0 = apply(X[(size_t)s0 * 32 + lane]);
        float4 v1 = apply(X[(size_t)s1 * 32 + lane]);
        float4 v2 = apply(X[(size_t)s2 * 32 + lane]);
        float4 v3 = apply(X[(size_t)s3 * 32 + lane]);
        add4(v0, v1); add4(v2, v3); add4(v0, v2); add4(acc, v0);
    }
    for (; e < e1; e++) {
        float4 v = apply(X[(size_t)csr[e] * 32 + lane]);
        add4(acc, v);
    }
    Z[(size_t)n * 32 + lane] = acc;
}

// ---------------- full GEMM: C[N,128] = act(A[N,128] @ W[128,128] + b) -------------
// 64-row tiles: 782 blocks (3.05/CU) for load balance; ~25 KB LDS -> high residency.
// REPACK: W points at h0_W1 [K=8][128][16]; virtual Wcat[f][c] = W1[c/16][f][c%16]
template <bool RELU, bool STATS, bool REPACK>
__global__ __launch_bounds__(256) void gemm128(const float* __restrict__ A,
                                               const float* __restrict__ W,
                                               const float* __restrict__ bias,
                                               float* __restrict__ C, int nrows,
                                               float* __restrict__ st) {
    __shared__ float As[64][33];   // row-major, +1 pad: conflict-free (R3-proven)
    __shared__ float Ws[32][128];
    int row0 = blockIdx.x * 64;
    int tid = threadIdx.x;
    int tr = (tid >> 4) << 2;  // 0..60 (4 rows/thread)
    int tc = (tid & 15) << 3;  // 0..120 (8 cols/thread)
    float acc[4][8];
#pragma unroll
    for (int i = 0; i < 4; i++)
#pragma unroll
        for (int j = 0; j < 8; j++) acc[i][j] = 0.f;

    for (int f0 = 0; f0 < 128; f0 += 32) {
        // stage A chunk [64 rows][32 feats]: 512 float4s, 2 per thread
#pragma unroll
        for (int i = 0; i < 2; i++) {
            int l = tid + i * 256;          // 0..511
            int r = l >> 3, q = l & 7;      // row, float4-col
            int gr = row0 + r;
            if (gr >= nrows) gr = nrows - 1;  // clamp (excluded from store/stats)
            float4 v = ((const float4*)A)[(size_t)gr * 32 + (f0 >> 2) + q];
            As[r][q * 4 + 0] = v.x;
            As[r][q * 4 + 1] = v.y;
            As[r][q * 4 + 2] = v.z;
            As[r][q * 4 + 3] = v.w;
        }
        // stage W chunk [32 feats][128 cols]: 1024 float4s, 4 per thread
#pragma unroll
        for (int i = 0; i < 4; i++) {
            int l = tid + i * 256;
            int f = l >> 5, q = l & 31;
            float4 wv;
            if (REPACK)
                wv = *(const float4*)&W[(q >> 2) * (FF * DD) + (size_t)(f0 + f) * DD + (q & 3) * 4];
            else
                wv = ((const float4*)W)[(size_t)(f0 + f) * 32 + q];
            ((float4*)&Ws[f][0])[q] = wv;
        }
        __syncthreads();
#pragma unroll 8
        for (int f = 0; f < 32; f++) {
            float a[4];
#pragma unroll
            for (int i = 0; i < 4; i++) a[i] = As[tr + i][f];
            float4 w04 = *(const float4*)&Ws[f][tc];
            float4 w48 = *(const float4*)&Ws[f][tc + 4];
            float w[8] = {w04.x, w04.y, w04.z, w04.w, w48.x, w48.y, w48.z, w48.w};
#pragma unroll
            for (int i = 0; i < 4; i++)
#pragma unroll
                for (int j = 0; j < 8; j++) acc[i][j] = fmaf(a[i], w[j], acc[i][j]);
        }
        __syncthreads();
    }

    float cs[8], cq[8];
#pragma unroll
    for (int j = 0; j < 8; j++) { cs[j] = 0.f; cq[j] = 0.f; }
#pragma unroll
    for (int i = 0; i < 4; i++) {
        int r = row0 + tr + i;
        if (r < nrows) {
#pragma unroll
            for (int j = 0; j < 8; j++) {
                float v = acc[i][j] + bias[tc + j];
                if (RELU) v = fmaxf(v, 0.f);
                C[(size_t)r * 128 + tc + j] = v;
                if (STATS) { cs[j] += v; cq[j] += v * v; }
            }
        }
    }
    if (STATS) {
        float* S1 = &As[0][0];   // 64*33=2112 >= 2048
        float* S2 = &Ws[0][0];
        int grp = tid >> 4;  // 0..15
        __syncthreads();
#pragma unroll
        for (int j = 0; j < 8; j++) {
            S1[grp * 128 + tc + j] = cs[j];
            S2[grp * 128 + tc + j] = cq[j];
        }
        __syncthreads();
        if (tid < 128) {
            float s = 0.f, q = 0.f;
#pragma unroll
            for (int gi = 0; gi < 16; gi++) {
                s += S1[gi * 128 + tid];
                q += S2[gi * 128 + tid];
            }
            atomicAdd(&st[tid], s);
            atomicAdd(&st[FF + tid], q);
        }
    }
}

#define KSTR 264  // padded k-block stride

// ---------------- block-diagonal GEMM (K blocks of 16x16), 8 nodes/block ----------
template <bool RELU>
__global__ __launch_bounds__(256) void k_bdgemm(const float4* __restrict__ A,
                                                const float* __restrict__ W,
                                                const float4* __restrict__ bias,
                                                float4* __restrict__ C) {
    __shared__ float As[8][128];
    __shared__ float Ws[KF * KSTR];
    int grp = threadIdx.x >> 5, lane = threadIdx.x & 31;
    int n = blockIdx.x * 8 + grp;
    ((float4*)&As[grp][0])[lane] = A[(size_t)n * 32 + lane];
    for (int l = threadIdx.x; l < KF * 256; l += 256) {
        int k = l >> 8, r = l & 255;
        Ws[k * KSTR + r] = W[l];
    }
    __syncthreads();
    int k = lane >> 2, jb = (lane & 3) * 4;
    float a[16];
    {
        const float4* As4 = (const float4*)&As[grp][k * 16];
        float4 a0 = As4[0], a1 = As4[1], a2 = As4[2], a3 = As4[3];
        a[0] = a0.x; a[1] = a0.y; a[2] = a0.z; a[3] = a0.w;
        a[4] = a1.x; a[5] = a1.y; a[6] = a1.z; a[7] = a1.w;
        a[8] = a2.x; a[9] = a2.y; a[10] = a2.z; a[11] = a2.w;
        a[12] = a3.x; a[13] = a3.y; a[14] = a3.z; a[15] = a3.w;
    }
    const float* wp = &Ws[k * KSTR + jb];
    float4 acc = bias[lane];
#pragma unroll
    for (int i = 0; i < 16; i++) {
        float4 wv = *(const float4*)&wp[i * 16];
        acc.x = fmaf(a[i], wv.x, acc.x);
        acc.y = fmaf(a[i], wv.y, acc.y);
        acc.z = fmaf(a[i], wv.z, acc.z);
        acc.w = fmaf(a[i], wv.w, acc.w);
    }
    if (RELU) {
        acc.x = fmaxf(acc.x, 0.f);
        acc.y = fmaxf(acc.y, 0.f);
        acc.z = fmaxf(acc.z, 0.f);
        acc.w = fmaxf(acc.w, 0.f);
    }
    C[(size_t)n * 32 + lane] = acc;
}

// ---------------- fused double block-diagonal GEMM ----------------
__global__ __launch_bounds__(256) void k_bdgemm2(const float4* __restrict__ A,
                                                 const float* __restrict__ W1,
                                                 const float4* __restrict__ b1,
                                                 const float* __restrict__ W2,
                                                 const float4* __restrict__ b2,
                                                 float4* __restrict__ C) {
    __shared__ float As[8][128];
    __shared__ float Ts[8][128];
    __shared__ float Ws1[KF * KSTR];
    __shared__ float Ws2[KF * KSTR];
    int grp = threadIdx.x >> 5, lane = threadIdx.x & 31;
    int n = blockIdx.x * 8 + grp;
    ((float4*)&As[grp][0])[lane] = A[(size_t)n * 32 + lane];
    for (int l = threadIdx.x; l < KF * 256; l += 256) {
        int k = l >> 8, r = l & 255;
        Ws1[k * KSTR + r] = W1[l];
        Ws2[k * KSTR + r] = W2[l];
    }
    __syncthreads();
    int k = lane >> 2, jb = (lane & 3) * 4;
    float a[16];
    {
        const float4* As4 = (const float4*)&As[grp][k * 16];
        float4 a0 = As4[0], a1 = As4[1], a2 = As4[2], a3 = As4[3];
        a[0] = a0.x; a[1] = a0.y; a[2] = a0.z; a[3] = a0.w;
        a[4] = a1.x; a[5] = a1.y; a[6] = a1.z; a[7] = a1.w;
        a[8] = a2.x; a[9] = a2.y; a[10] = a2.z; a[11] = a2.w;
        a[12] = a3.x; a[13] = a3.y; a[14] = a3.z; a[15] = a3.w;
    }
    const float* wp1 = &Ws1[k * KSTR + jb];
    float4 t = b1[lane];
#pragma unroll
    for (int i = 0; i < 16; i++) {
        float4 wv = *(const float4*)&wp1[i * 16];
        t.x = fmaf(a[i], wv.x, t.x);
        t.y = fmaf(a[i], wv.y, t.y);
        t.z = fmaf(a[i], wv.z, t.z);
        t.w = fmaf(a[i], wv.w, t.w);
    }
    t.x = fmaxf(t.x, 0.f); t.y = fmaxf(t.y, 0.f);
    t.z = fmaxf(t.z, 0.f); t.w = fmaxf(t.w, 0.f);
    ((float4*)&Ts[grp][0])[lane] = t;
    __syncthreads();
    float b[16];
    {
        const float4* Ts4 = (const float4*)&Ts[grp][k * 16];
        float4 a0 = Ts4[0], a1 = Ts4[1], a2 = Ts4[2], a3 = Ts4[3];
        b[0] = a0.x; b[1] = a0.y; b[2] = a0.z; b[3] = a0.w;
        b[4] = a1.x; b[5] = a1.y; b[6] = a1.z; b[7] = a1.w;
        b[8] = a2.x; b[9] = a2.y; b[10] = a2.z; b[11] = a2.w;
        b[12] = a3.x; b[13] = a3.y; b[14] = a3.z; b[15] = a3.w;
    }
    const float* wp2 = &Ws2[k * KSTR + jb];
    float4 acc = b2[lane];
#pragma unroll
    for (int i = 0; i < 16; i++) {
        float4 wv = *(const float4*)&wp2[i * 16];
        acc.x = fmaf(b[i], wv.x, acc.x);
        acc.y = fmaf(b[i], wv.y, acc.y);
        acc.z = fmaf(b[i], wv.z, acc.z);
        acc.w = fmaf(b[i], wv.w, acc.w);
    }
    C[(size_t)n * 32 + lane] = acc;
}

// ---------------- BN stats (standalone, for bdgemm outputs) ----------------
__global__ __launch_bounds__(256) void k_stats(const float* __restrict__ X,
                                               float* __restrict__ st, int nrows) {
    int c = threadIdx.x & 127;
    int half = threadIdx.x >> 7;
    int rpb = (nrows + gridDim.x - 1) / gridDim.x;
    int r0 = blockIdx.x * rpb;
    int r1 = min(r0 + rpb, nrows);
    float s = 0.f, sq = 0.f;
    for (int r = r0 + half; r < r1; r += 2) {
        float v = X[(size_t)r * FF + c];
        s += v;
        sq += v * v;
    }
    atomicAdd(&st[c], s);
    atomicAdd(&st[FF + c], sq);
}

// ---------------- pooling with fused final BN ----------------
__global__ __launch_bounds__(128) void k_pool(const float* __restrict__ X,
                                              const int* __restrict__ batch,
                                              const float* __restrict__ st,
                                              const float* __restrict__ g,
                                              const float* __restrict__ be,
                                              float* __restrict__ out) {
    int c = threadIdx.x;
    const float inv_n = 1.0f / (float)NN;
    float mu = st[c] * inv_n;
    float var = st[FF + c] * inv_n - mu * mu;
    float a = g[c] * rsqrtf(var + BN_EPS);
    float b = be[c] - mu * a;
    int chunk = (NN + gridDim.x - 1) / gridDim.x;
    int r0 = blockIdx.x * chunk;
    int r1 = min(r0 + chunk, NN);
    if (r0 >= r1) return;
    float acc = 0.f;
    int cnt = 0;
    int cur = batch[r0];
    for (int r = r0; r < r1; r++) {
        int bb = batch[r];
        if (bb != cur) {
            atomicAdd(&out[(size_t)cur * FF + c], fmaf(a, acc, b * (float)cnt));
            acc = 0.f;
            cnt = 0;
            cur = bb;
        }
        acc += X[(size_t)r * FF + c];
        cnt++;
    }
    atomicAdd(&out[(size_t)cur * FF + c], fmaf(a, acc, b * (float)cnt));
}

extern "C" void kernel_launch(void* const* d_in, const int* in_sizes, int n_in,
                              void* d_out, int out_size, void* d_ws, size_t ws_size,
                              hipStream_t stream) {
    const float* x = (const float*)d_in[0];
    const int* ei = (const int*)d_in[1];
    const int* src = ei;
    const int* dst = ei + NE;
    const int* batch = (const int*)d_in[2];
    const float* gc_W1 = (const float*)d_in[4];
    const float* gc_b1 = (const float*)d_in[5];
    const float* gc_W2 = (const float*)d_in[6];
    const float* gc_b2 = (const float*)d_in[7];
    const float* gc_g = (const float*)d_in[8];
    const float* gc_be = (const float*)d_in[9];
    const float* h0_W1 = (const float*)d_in[10];
    const float* h0_b1 = (const float*)d_in[11];
    const float* h0_W2 = (const float*)d_in[12];
    const float* h0_b2 = (const float*)d_in[13];
    const float* h0_g = (const float*)d_in[14];
    const float* h0_be = (const float*)d_in[15];
    const float* h1_W1 = (const float*)d_in[16];
    const float* h1_b1 = (const float*)d_in[17];
    const float* h1_W2 = (const float*)d_in[18];
    const float* h1_b2 = (const float*)d_in[19];
    const float* h1_g = (const float*)d_in[20];
    const float* h1_be = (const float*)d_in[21];

    const size_t NF = (size_t)NN * FF;
    float* P0 = (float*)d_ws;
    float* P1 = P0 + NF;
    float* P2 = P1 + NF;
    float* stats = P2 + NF;
    int* deg = (int*)(stats + 5 * 256);
    int* cnt = deg + NN;
    int* offs = cnt + NN;
    int* bsum = offs + (NN + 4);
    int* boffs = bsum + 256;
    int* csr = boffs + 256;

    hipMemsetAsync(deg, 0, (size_t)2 * NN * sizeof(int), stream);
    hipMemsetAsync(stats, 0, 5 * 256 * sizeof(float), stream);
    hipMemsetAsync(d_out, 0, (size_t)GG * KF * DD * sizeof(float), stream);

    k_deg<<<(NE + 255) / 256, 256, 0, stream>>>(dst, deg);
    k_bsum<<<NB, 256, 0, stream>>>(deg, bsum);
    k_bscan<<<1, 256, 0, stream>>>(bsum, boffs);
    k_offs<<<NB, 256, 0, stream>>>(deg, boffs, offs);
    k_fill<<<(NE + 255) / 256, 256, 0, stream>>>(src, dst, offs, cnt, csr);

    const int agg_grid = NN / 8;            // 6250
    const int gemm_grid = (NN + 63) / 64;   // 782: 3.05 blocks/CU, good balance

    // ---- GC layers ----
    k_agg<false, false><<<agg_grid, 256, 0, stream>>>(
        (const float4*)x, offs, csr, nullptr, nullptr, nullptr, (float4*)P0);
    gemm128<true, false, false><<<gemm_grid, 256, 0, stream>>>(P0, gc_W1, gc_b1, P1, NN, nullptr);
    gemm128<false, true, false><<<gemm_grid, 256, 0, stream>>>(P1, gc_W2, gc_b2, P2, NN, stats);

    k_agg<true, true><<<agg_grid, 256, 0, stream>>>(
        (const float4*)P2, offs, csr, stats, gc_g, gc_be, (float4*)P0);
    gemm128<true, false, false><<<gemm_grid, 256, 0, stream>>>(P0, gc_W1 + FF * FF, gc_b1 + FF, P1, NN, nullptr);
    gemm128<false, true, false><<<gemm_grid, 256, 0, stream>>>(P1, gc_W2 + FF * FF, gc_b2 + FF, P2, NN, stats + 256);

    k_agg<true, true><<<agg_grid, 256, 0, stream>>>(
        (const float4*)P2, offs, csr, stats + 256, gc_g + FF, gc_be + FF, (float4*)P0);
    gemm128<true, false, false><<<gemm_grid, 256, 0, stream>>>(P0, gc_W1 + 2 * FF * FF, gc_b1 + 2 * FF, P1, NN, nullptr);
    gemm128<false, true, false><<<gemm_grid, 256, 0, stream>>>(P1, gc_W2 + 2 * FF * FF, gc_b2 + 2 * FF, P2, NN, stats + 512);

    // ---- head layer 0 (repack fused into W staging) ----
    k_agg<true, false><<<agg_grid, 256, 0, stream>>>(
        (const float4*)P2, offs, csr, stats + 512, gc_g + 2 * FF, gc_be + 2 * FF, (float4*)P0);
    gemm128<true, false, true><<<gemm_grid, 256, 0, stream>>>(P0, h0_W1, h0_b1, P1, NN, nullptr);
    k_bdgemm<false><<<agg_grid, 256, 0, stream>>>((const float4*)P1, h0_W2, (const float4*)h0_b2, (float4*)P2);
    k_stats<<<256, 256, 0, stream>>>(P2, stats + 768, NN);

    // ---- head layer 1 (fused bdgemm pair) ----
    k_agg<true, true><<<agg_grid, 256, 0, stream>>>(
        (const float4*)P2, offs, csr, stats + 768, h0_g, h0_be, (float4*)P0);
    k_bdgemm2<<<agg_grid, 256, 0, stream>>>((const float4*)P0, h1_W1, (const float4*)h1_b1,
                                            h1_W2, (const float4*)h1_b2, (float4*)P1);
    k_stats<<<256, 256, 0, stream>>>(P1, stats + 1024, NN);

    // ---- pool with fused final BN ----
    k_pool<<<512, 128, 0, stream>>>(P1, batch, stats + 1024, h1_g, h1_be, (float*)d_out);
}

// Round 6
// 807.769 us; speedup vs baseline: 1.0834x; 1.0834x over previous
//
#include <hip/hip_runtime.h>

#define NN 50000
#define NE 800000
#define FF 128
#define KF 8
#define DD 16
#define GG 512
#define BN_EPS 1e-5f
#define NB 196   // ceil(NN/256)
#define KSTR 264 // padded k-block stride for block-diag weights

// ---------------- CSR build ----------------
__global__ void k_deg(const int* __restrict__ dst, int* __restrict__ deg) {
    int e = blockIdx.x * 256 + threadIdx.x;
    if (e < NE) atomicAdd(&deg[dst[e]], 1);
}

__global__ __launch_bounds__(256) void k_bsum(const int* __restrict__ deg, int* __restrict__ bsum) {
    int idx = blockIdx.x * 256 + threadIdx.x;
    int v = (idx < NN) ? deg[idx] : 0;
#pragma unroll
    for (int off = 32; off; off >>= 1) v += __shfl_down(v, off, 64);
    __shared__ int ws[4];
    if ((threadIdx.x & 63) == 0) ws[threadIdx.x >> 6] = v;
    __syncthreads();
    if (threadIdx.x == 0) bsum[blockIdx.x] = ws[0] + ws[1] + ws[2] + ws[3];
}

__global__ __launch_bounds__(256) void k_bscan(const int* __restrict__ bsum, int* __restrict__ boffs) {
    __shared__ int s[256];
    int tid = threadIdx.x;
    int v = (tid < NB) ? bsum[tid] : 0;
    s[tid] = v;
    __syncthreads();
    for (int off = 1; off < 256; off <<= 1) {
        int t = (tid >= off) ? s[tid - off] : 0;
        __syncthreads();
        s[tid] += t;
        __syncthreads();
    }
    if (tid < NB) boffs[tid] = s[tid] - v;  // exclusive
}

__global__ __launch_bounds__(256) void k_offs(const int* __restrict__ deg,
                                              const int* __restrict__ boffs,
                                              int* __restrict__ offs) {
    __shared__ int s[256];
    int tid = threadIdx.x;
    int idx = blockIdx.x * 256 + tid;
    int v = (idx < NN) ? deg[idx] : 0;
    s[tid] = v;
    __syncthreads();
    for (int off = 1; off < 256; off <<= 1) {
        int t = (tid >= off) ? s[tid - off] : 0;
        __syncthreads();
        s[tid] += t;
        __syncthreads();
    }
    int incl = s[tid];
    if (idx < NN) offs[idx] = boffs[blockIdx.x] + incl - v;
    if (idx == NN - 1) offs[NN] = boffs[blockIdx.x] + incl;
}

__global__ void k_fill(const int* __restrict__ src, const int* __restrict__ dst,
                       const int* __restrict__ offs, int* __restrict__ cnt,
                       int* __restrict__ csr) {
    int e = blockIdx.x * 256 + threadIdx.x;
    if (e < NE) {
        int d = dst[e];
        int p = atomicAdd(&cnt[d], 1);
        csr[offs[d] + p] = src[e];
    }
}

// ---------------- shared device helpers ----------------
__device__ __forceinline__ void bn_coefs(const float* st, const float* g, const float* be,
                                         int lane, float4& a4, float4& b4) {
    const float inv_n = 1.0f / (float)NN;
    float av[4], bv[4];
#pragma unroll
    for (int t = 0; t < 4; t++) {
        int c = lane * 4 + t;
        float mu = st[c] * inv_n;
        float var = st[FF + c] * inv_n - mu * mu;
        float a = g[c] * rsqrtf(var + BN_EPS);
        av[t] = a;
        bv[t] = be[c] - mu * a;
    }
    a4 = make_float4(av[0], av[1], av[2], av[3]);
    b4 = make_float4(bv[0], bv[1], bv[2], bv[3]);
}

// ---------------- aggregation with fused (optional) BN affine (+relu) on load ------
// R3-proven config: unroll 8, occ ~65% — at the gather plateau (~3.6 TB/s L2-miss BW,
// FETCH == per-XCD compulsory floor)
template <bool BN, bool RELU>
__global__ __launch_bounds__(256) void k_agg(const float4* __restrict__ X,
                                             const int* __restrict__ offs,
                                             const int* __restrict__ csr,
                                             const float* __restrict__ st,
                                             const float* __restrict__ g,
                                             const float* __restrict__ be,
                                             float4* __restrict__ Z) {
    int grp = threadIdx.x >> 5;
    int lane = threadIdx.x & 31;
    int n = blockIdx.x * 8 + grp;

    float4 a4 = make_float4(1.f, 1.f, 1.f, 1.f);
    float4 b4 = make_float4(0.f, 0.f, 0.f, 0.f);
    if (BN) bn_coefs(st, g, be, lane, a4, b4);

    auto apply = [&](float4 v) -> float4 {
        if (BN) {
            v.x = fmaf(v.x, a4.x, b4.x);
            v.y = fmaf(v.y, a4.y, b4.y);
            v.z = fmaf(v.z, a4.z, b4.z);
            v.w = fmaf(v.w, a4.w, b4.w);
        }
        if (RELU) {
            v.x = fmaxf(v.x, 0.f);
            v.y = fmaxf(v.y, 0.f);
            v.z = fmaxf(v.z, 0.f);
            v.w = fmaxf(v.w, 0.f);
        }
        return v;
    };
    auto add4 = [](float4& a, float4 b) {
        a.x += b.x; a.y += b.y; a.z += b.z; a.w += b.w;
    };

    float4 acc = apply(X[(size_t)n * 32 + lane]);
    int e0 = offs[n], e1 = offs[n + 1];
    int e = e0;
    for (; e + 8 <= e1; e += 8) {
        int s0 = csr[e], s1 = csr[e + 1], s2 = csr[e + 2], s3 = csr[e + 3];
        int s4 = csr[e + 4], s5 = csr[e + 5], s6 = csr[e + 6], s7 = csr[e + 7];
        float4 v0 = X[(size_t)s0 * 32 + lane];
        float4 v1 = X[(size_t)s1 * 32 + lane];
        float4 v2 = X[(size_t)s2 * 32 + lane];
        float4 v3 = X[(size_t)s3 * 32 + lane];
        float4 v4 = X[(size_t)s4 * 32 + lane];
        float4 v5 = X[(size_t)s5 * 32 + lane];
        float4 v6 = X[(size_t)s6 * 32 + lane];
        float4 v7 = X[(size_t)s7 * 32 + lane];
        v0 = apply(v0); v1 = apply(v1); v2 = apply(v2); v3 = apply(v3);
        v4 = apply(v4); v5 = apply(v5); v6 = apply(v6); v7 = apply(v7);
        add4(v0, v1); add4(v2, v3); add4(v4, v5); add4(v6, v7);
        add4(v0, v2); add4(v4, v6); add4(v0, v4); add4(acc, v0);
    }
    for (; e + 4 <= e1; e += 4) {
        int s0 = csr[e], s1 = csr[e + 1], s2 = csr[e + 2], s3 = csr[e + 3];
        float4 v0 = apply(X[(size_t)s0 * 32 + lane]);
        float4 v1 = apply(X[(size_t)s1 * 32 + lane]);
        float4 v2 = apply(X[(size_t)s2 * 32 + lane]);
        float4 v3 = apply(X[(size_t)s3 * 32 + lane]);
        add4(v0, v1); add4(v2, v3); add4(v0, v2); add4(acc, v0);
    }
    for (; e < e1; e++) {
        float4 v = apply(X[(size_t)csr[e] * 32 + lane]);
        add4(acc, v);
    }
    Z[(size_t)n * 32 + lane] = acc;
}

// ---------------- fused GEMM pair: C = relu(A@W1+b1)@W2 + b2, + stats --------------
// 64-row tiles, 782 blocks. z tile kept in LDS (no global round-trip).
// A chunk staged f-major -> a-frag is one ds_read_b128 (4 consecutive rows).
__global__ __launch_bounds__(256) void gemm_pair(const float* __restrict__ A,
                                                 const float* __restrict__ W1,
                                                 const float* __restrict__ b1,
                                                 const float* __restrict__ W2,
                                                 const float* __restrict__ b2,
                                                 float* __restrict__ C, int nrows,
                                                 float* __restrict__ st) {
    __shared__ float Af[32][68];    // A chunk, f-major (b128 a-frag reads)
    __shared__ float Ws[32][128];   // weight chunk (W1 then W2)
    __shared__ float Zs[64][133];   // z tile, row-major, odd pad: conflict-free r/w
    int row0 = blockIdx.x * 64;
    int tid = threadIdx.x;
    int tr = (tid >> 4) << 2;  // 4 rows/thread
    int tc = (tid & 15) << 3;  // 8 cols/thread
    float acc[4][8];
#pragma unroll
    for (int i = 0; i < 4; i++)
#pragma unroll
        for (int j = 0; j < 8; j++) acc[i][j] = 0.f;

    // ---- phase 1: z = relu(A@W1 + b1) ----
    for (int f0 = 0; f0 < 128; f0 += 32) {
#pragma unroll
        for (int i = 0; i < 2; i++) {
            int l = tid + i * 256;          // 0..511
            int r = l >> 3, q = l & 7;
            int gr = row0 + r;
            if (gr >= nrows) gr = nrows - 1;
            float4 v = ((const float4*)A)[(size_t)gr * 32 + (f0 >> 2) + q];
            Af[q * 4 + 0][r] = v.x;
            Af[q * 4 + 1][r] = v.y;
            Af[q * 4 + 2][r] = v.z;
            Af[q * 4 + 3][r] = v.w;
        }
#pragma unroll
        for (int i = 0; i < 4; i++) {
            int l = tid + i * 256;
            int f = l >> 5, q = l & 31;
            ((float4*)&Ws[f][0])[q] = ((const float4*)W1)[(size_t)(f0 + f) * 32 + q];
        }
        __syncthreads();
#pragma unroll 8
        for (int f = 0; f < 32; f++) {
            float4 a04 = *(const float4*)&Af[f][tr];
            float a[4] = {a04.x, a04.y, a04.z, a04.w};
            float4 w04 = *(const float4*)&Ws[f][tc];
            float4 w48 = *(const float4*)&Ws[f][tc + 4];
            float w[8] = {w04.x, w04.y, w04.z, w04.w, w48.x, w48.y, w48.z, w48.w};
#pragma unroll
            for (int i = 0; i < 4; i++)
#pragma unroll
                for (int j = 0; j < 8; j++) acc[i][j] = fmaf(a[i], w[j], acc[i][j]);
        }
        __syncthreads();
    }
    // write z = relu(acc + b1) into Zs (b32 stores: 2-way conflicts only, free)
#pragma unroll
    for (int i = 0; i < 4; i++)
#pragma unroll
        for (int j = 0; j < 8; j++)
            Zs[tr + i][tc + j] = fmaxf(acc[i][j] + b1[tc + j], 0.f);

#pragma unroll
    for (int i = 0; i < 4; i++)
#pragma unroll
        for (int j = 0; j < 8; j++) acc[i][j] = 0.f;

    // ---- phase 2: C = z@W2 + b2 ----
    for (int f0 = 0; f0 < 128; f0 += 32) {
#pragma unroll
        for (int i = 0; i < 4; i++) {
            int l = tid + i * 256;
            int f = l >> 5, q = l & 31;
            ((float4*)&Ws[f][0])[q] = ((const float4*)W2)[(size_t)(f0 + f) * 32 + q];
        }
        __syncthreads();  // covers Zs visibility on first iter + Ws swap
#pragma unroll 8
        for (int f = 0; f < 32; f++) {
            float a[4];
#pragma unroll
            for (int i = 0; i < 4; i++) a[i] = Zs[tr + i][f0 + f];
            float4 w04 = *(const float4*)&Ws[f][tc];
            float4 w48 = *(const float4*)&Ws[f][tc + 4];
            float w[8] = {w04.x, w04.y, w04.z, w04.w, w48.x, w48.y, w48.z, w48.w};
#pragma unroll
            for (int i = 0; i < 4; i++)
#pragma unroll
                for (int j = 0; j < 8; j++) acc[i][j] = fmaf(a[i], w[j], acc[i][j]);
        }
        __syncthreads();
    }

    // ---- epilogue: bias, store, fused stats ----
    float cs[8], cq[8];
#pragma unroll
    for (int j = 0; j < 8; j++) { cs[j] = 0.f; cq[j] = 0.f; }
#pragma unroll
    for (int i = 0; i < 4; i++) {
        int r = row0 + tr + i;
        if (r < nrows) {
#pragma unroll
            for (int j = 0; j < 8; j++) {
                float v = acc[i][j] + b2[tc + j];
                C[(size_t)r * 128 + tc + j] = v;
                cs[j] += v;
                cq[j] += v * v;
            }
        }
    }
    {
        float* S1 = &Af[0][0];   // 32*68=2176 >= 2048
        float* S2 = &Ws[0][0];
        int grp = tid >> 4;
        __syncthreads();
#pragma unroll
        for (int j = 0; j < 8; j++) {
            S1[grp * 128 + tc + j] = cs[j];
            S2[grp * 128 + tc + j] = cq[j];
        }
        __syncthreads();
        if (tid < 128) {
            float s = 0.f, q = 0.f;
#pragma unroll
            for (int gi = 0; gi < 16; gi++) {
                s += S1[gi * 128 + tid];
                q += S2[gi * 128 + tid];
            }
            atomicAdd(&st[tid], s);
            atomicAdd(&st[FF + tid], q);
        }
    }
}

// ---------------- fused h0: C = relu(A@W1cat+b1) @ blockdiag(W2) + b2, + stats -----
// W1 read directly in [K,F,d] layout (repack fused into staging).
__global__ __launch_bounds__(256) void gemm_h0(const float* __restrict__ A,
                                               const float* __restrict__ W1,  // [K,F,d]
                                               const float* __restrict__ b1,  // [K*d]
                                               const float* __restrict__ W2,  // [K,d,d]
                                               const float* __restrict__ b2,  // [K*d]
                                               float* __restrict__ C, int nrows,
                                               float* __restrict__ st) {
    __shared__ float Af[32][68];
    __shared__ float Ws[32][128];   // W1 chunks; later reused flat for W2 (KSTR) + stats
    __shared__ float Zs[64][133];
    int row0 = blockIdx.x * 64;
    int tid = threadIdx.x;
    int tr = (tid >> 4) << 2;
    int tc = (tid & 15) << 3;
    float acc[4][8];
#pragma unroll
    for (int i = 0; i < 4; i++)
#pragma unroll
        for (int j = 0; j < 8; j++) acc[i][j] = 0.f;

    for (int f0 = 0; f0 < 128; f0 += 32) {
#pragma unroll
        for (int i = 0; i < 2; i++) {
            int l = tid + i * 256;
            int r = l >> 3, q = l & 7;
            int gr = row0 + r;
            if (gr >= nrows) gr = nrows - 1;
            float4 v = ((const float4*)A)[(size_t)gr * 32 + (f0 >> 2) + q];
            Af[q * 4 + 0][r] = v.x;
            Af[q * 4 + 1][r] = v.y;
            Af[q * 4 + 2][r] = v.z;
            Af[q * 4 + 3][r] = v.w;
        }
#pragma unroll
        for (int i = 0; i < 4; i++) {
            int l = tid + i * 256;
            int f = l >> 5, q = l & 31;
            // repack: Wcat[f][c], c=q*4..q*4+3, k=c>>4=q>>2, j=c&15=(q&3)*4..
            float4 wv = *(const float4*)&W1[(q >> 2) * (FF * DD) + (size_t)(f0 + f) * DD + (q & 3) * 4];
            ((float4*)&Ws[f][0])[q] = wv;
        }
        __syncthreads();
#pragma unroll 8
        for (int f = 0; f < 32; f++) {
            float4 a04 = *(const float4*)&Af[f][tr];
            float a[4] = {a04.x, a04.y, a04.z, a04.w};
            float4 w04 = *(const float4*)&Ws[f][tc];
            float4 w48 = *(const float4*)&Ws[f][tc + 4];
            float w[8] = {w04.x, w04.y, w04.z, w04.w, w48.x, w48.y, w48.z, w48.w};
#pragma unroll
            for (int i = 0; i < 4; i++)
#pragma unroll
                for (int j = 0; j < 8; j++) acc[i][j] = fmaf(a[i], w[j], acc[i][j]);
        }
        __syncthreads();
    }
#pragma unroll
    for (int i = 0; i < 4; i++)
#pragma unroll
        for (int j = 0; j < 8; j++)
            Zs[tr + i][tc + j] = fmaxf(acc[i][j] + b1[tc + j], 0.f);

    // stage W2 [K,16,16] into Ws flat with KSTR padding
    float* W2s = &Ws[0][0];
    for (int l = tid; l < KF * 256; l += 256) {
        int k = l >> 8, r = l & 255;
        W2s[k * KSTR + r] = W2[l];
    }
    __syncthreads();

    // block-diag product: y[r][c] = sum_i Zs[r][k*16+i] * W2[k][i][c&15]
    int k = tc >> 4;            // factor
    int lo = tc & 15;           // 0 or 8
    float y[4][8];
#pragma unroll
    for (int i = 0; i < 4; i++)
#pragma unroll
        for (int j = 0; j < 8; j++) y[i][j] = 0.f;
#pragma unroll
    for (int ii = 0; ii < 16; ii++) {
        float a[4];
#pragma unroll
        for (int i = 0; i < 4; i++) a[i] = Zs[tr + i][k * 16 + ii];
        float4 w04 = *(const float4*)&W2s[k * KSTR + ii * 16 + lo];
        float4 w48 = *(const float4*)&W2s[k * KSTR + ii * 16 + lo + 4];
        float w[8] = {w04.x, w04.y, w04.z, w04.w, w48.x, w48.y, w48.z, w48.w};
#pragma unroll
        for (int i = 0; i < 4; i++)
#pragma unroll
            for (int j = 0; j < 8; j++) y[i][j] = fmaf(a[i], w[j], y[i][j]);
    }

    float cs[8], cq[8];
#pragma unroll
    for (int j = 0; j < 8; j++) { cs[j] = 0.f; cq[j] = 0.f; }
#pragma unroll
    for (int i = 0; i < 4; i++) {
        int r = row0 + tr + i;
        if (r < nrows) {
#pragma unroll
            for (int j = 0; j < 8; j++) {
                float v = y[i][j] + b2[tc + j];
                C[(size_t)r * 128 + tc + j] = v;
                cs[j] += v;
                cq[j] += v * v;
            }
        }
    }
    {
        float* S1 = &Af[0][0];
        float* S2 = &Zs[0][0];  // reuse Zs as scratch (done with it)
        int grp = tid >> 4;
        __syncthreads();
#pragma unroll
        for (int j = 0; j < 8; j++) {
            S1[grp * 128 + tc + j] = cs[j];
            S2[grp * 128 + tc + j] = cq[j];
        }
        __syncthreads();
        if (tid < 128) {
            float s = 0.f, q = 0.f;
#pragma unroll
            for (int gi = 0; gi < 16; gi++) {
                s += S1[gi * 128 + tid];
                q += S2[gi * 128 + tid];
            }
            atomicAdd(&st[tid], s);
            atomicAdd(&st[FF + tid], q);
        }
    }
}

// ---------------- fused h1: agg(BN+relu on load) + double block-diag MLP -----------
__global__ __launch_bounds__(256) void k_aggbd(const float4* __restrict__ X,
                                               const int* __restrict__ offs,
                                               const int* __restrict__ csr,
                                               const float* __restrict__ st,
                                               const float* __restrict__ g,
                                               const float* __restrict__ be,
                                               const float* __restrict__ W1,
                                               const float4* __restrict__ b1,
                                               const float* __restrict__ W2,
                                               const float4* __restrict__ b2,
                                               float4* __restrict__ C) {
    __shared__ float As[8][128];
    __shared__ float Ts[8][128];
    __shared__ float Ws1[KF * KSTR];
    __shared__ float Ws2[KF * KSTR];
    int grp = threadIdx.x >> 5, lane = threadIdx.x & 31;
    int n = blockIdx.x * 8 + grp;

    // stage weights (overlaps with gather latency)
    for (int l = threadIdx.x; l < KF * 256; l += 256) {
        int k = l >> 8, r = l & 255;
        Ws1[k * KSTR + r] = W1[l];
        Ws2[k * KSTR + r] = W2[l];
    }

    float4 a4, b4;
    bn_coefs(st, g, be, lane, a4, b4);
    auto apply = [&](float4 v) -> float4 {
        v.x = fmaxf(fmaf(v.x, a4.x, b4.x), 0.f);
        v.y = fmaxf(fmaf(v.y, a4.y, b4.y), 0.f);
        v.z = fmaxf(fmaf(v.z, a4.z, b4.z), 0.f);
        v.w = fmaxf(fmaf(v.w, a4.w, b4.w), 0.f);
        return v;
    };
    auto add4 = [](float4& a, float4 b) {
        a.x += b.x; a.y += b.y; a.z += b.z; a.w += b.w;
    };

    float4 acc = apply(X[(size_t)n * 32 + lane]);
    int e0 = offs[n], e1 = offs[n + 1];
    int e = e0;
    for (; e + 8 <= e1; e += 8) {
        int s0 = csr[e], s1 = csr[e + 1], s2 = csr[e + 2], s3 = csr[e + 3];
        int s4 = csr[e + 4], s5 = csr[e + 5], s6 = csr[e + 6], s7 = csr[e + 7];
        float4 v0 = X[(size_t)s0 * 32 + lane];
        float4 v1 = X[(size_t)s1 * 32 + lane];
        float4 v2 = X[(size_t)s2 * 32 + lane];
        float4 v3 = X[(size_t)s3 * 32 + lane];
        float4 v4 = X[(size_t)s4 * 32 + lane];
        float4 v5 = X[(size_t)s5 * 32 + lane];
        float4 v6 = X[(size_t)s6 * 32 + lane];
        float4 v7 = X[(size_t)s7 * 32 + lane];
        v0 = apply(v0); v1 = apply(v1); v2 = apply(v2); v3 = apply(v3);
        v4 = apply(v4); v5 = apply(v5); v6 = apply(v6); v7 = apply(v7);
        add4(v0, v1); add4(v2, v3); add4(v4, v5); add4(v6, v7);
        add4(v0, v2); add4(v4, v6); add4(v0, v4); add4(acc, v0);
    }
    for (; e + 4 <= e1; e += 4) {
        int s0 = csr[e], s1 = csr[e + 1], s2 = csr[e + 2], s3 = csr[e + 3];
        float4 v0 = apply(X[(size_t)s0 * 32 + lane]);
        float4 v1 = apply(X[(size_t)s1 * 32 + lane]);
        float4 v2 = apply(X[(size_t)s2 * 32 + lane]);
        float4 v3 = apply(X[(size_t)s3 * 32 + lane]);
        add4(v0, v1); add4(v2, v3); add4(v0, v2); add4(acc, v0);
    }
    for (; e < e1; e++) {
        float4 v = apply(X[(size_t)csr[e] * 32 + lane]);
        add4(acc, v);
    }
    ((float4*)&As[grp][0])[lane] = acc;
    __syncthreads();

    // t = relu(z @ bd(W1) + b1)
    int k = lane >> 2, jb = (lane & 3) * 4;
    float a[16];
    {
        const float4* As4 = (const float4*)&As[grp][k * 16];
        float4 a0 = As4[0], a1 = As4[1], a2 = As4[2], a3 = As4[3];
        a[0] = a0.x; a[1] = a0.y; a[2] = a0.z; a[3] = a0.w;
        a[4] = a1.x; a[5] = a1.y; a[6] = a1.z; a[7] = a1.w;
        a[8] = a2.x; a[9] = a2.y; a[10] = a2.z; a[11] = a2.w;
        a[12] = a3.x; a[13] = a3.y; a[14] = a3.z; a[15] = a3.w;
    }
    const float* wp1 = &Ws1[k * KSTR + jb];
    float4 t = b1[lane];
#pragma unroll
    for (int i = 0; i < 16; i++) {
        float4 wv = *(const float4*)&wp1[i * 16];
        t.x = fmaf(a[i], wv.x, t.x);
        t.y = fmaf(a[i], wv.y, t.y);
        t.z = fmaf(a[i], wv.z, t.z);
        t.w = fmaf(a[i], wv.w, t.w);
    }
    t.x = fmaxf(t.x, 0.f); t.y = fmaxf(t.y, 0.f);
    t.z = fmaxf(t.z, 0.f); t.w = fmaxf(t.w, 0.f);
    ((float4*)&Ts[grp][0])[lane] = t;
    __syncthreads();

    float b[16];
    {
        const float4* Ts4 = (const float4*)&Ts[grp][k * 16];
        float4 a0 = Ts4[0], a1 = Ts4[1], a2 = Ts4[2], a3 = Ts4[3];
        b[0] = a0.x; b[1] = a0.y; b[2] = a0.z; b[3] = a0.w;
        b[4] = a1.x; b[5] = a1.y; b[6] = a1.z; b[7] = a1.w;
        b[8] = a2.x; b[9] = a2.y; b[10] = a2.z; b[11] = a2.w;
        b[12] = a3.x; b[13] = a3.y; b[14] = a3.z; b[15] = a3.w;
    }
    const float* wp2 = &Ws2[k * KSTR + jb];
    float4 acc2 = b2[lane];
#pragma unroll
    for (int i = 0; i < 16; i++) {
        float4 wv = *(const float4*)&wp2[i * 16];
        acc2.x = fmaf(b[i], wv.x, acc2.x);
        acc2.y = fmaf(b[i], wv.y, acc2.y);
        acc2.z = fmaf(b[i], wv.z, acc2.z);
        acc2.w = fmaf(b[i], wv.w, acc2.w);
    }
    C[(size_t)n * 32 + lane] = acc2;
}

// ---------------- BN stats (standalone, for k_aggbd output) ----------------
__global__ __launch_bounds__(256) void k_stats(const float* __restrict__ X,
                                               float* __restrict__ st, int nrows) {
    int c = threadIdx.x & 127;
    int half = threadIdx.x >> 7;
    int rpb = (nrows + gridDim.x - 1) / gridDim.x;
    int r0 = blockIdx.x * rpb;
    int r1 = min(r0 + rpb, nrows);
    float s = 0.f, sq = 0.f;
    for (int r = r0 + half; r < r1; r += 2) {
        float v = X[(size_t)r * FF + c];
        s += v;
        sq += v * v;
    }
    atomicAdd(&st[c], s);
    atomicAdd(&st[FF + c], sq);
}

// ---------------- pooling with fused final BN ----------------
__global__ __launch_bounds__(128) void k_pool(const float* __restrict__ X,
                                              const int* __restrict__ batch,
                                              const float* __restrict__ st,
                                              const float* __restrict__ g,
                                              const float* __restrict__ be,
                                              float* __restrict__ out) {
    int c = threadIdx.x;
    const float inv_n = 1.0f / (float)NN;
    float mu = st[c] * inv_n;
    float var = st[FF + c] * inv_n - mu * mu;
    float a = g[c] * rsqrtf(var + BN_EPS);
    float b = be[c] - mu * a;
    int chunk = (NN + gridDim.x - 1) / gridDim.x;
    int r0 = blockIdx.x * chunk;
    int r1 = min(r0 + chunk, NN);
    if (r0 >= r1) return;
    float acc = 0.f;
    int cnt = 0;
    int cur = batch[r0];
    for (int r = r0; r < r1; r++) {
        int bb = batch[r];
        if (bb != cur) {
            atomicAdd(&out[(size_t)cur * FF + c], fmaf(a, acc, b * (float)cnt));
            acc = 0.f;
            cnt = 0;
            cur = bb;
        }
        acc += X[(size_t)r * FF + c];
        cnt++;
    }
    atomicAdd(&out[(size_t)cur * FF + c], fmaf(a, acc, b * (float)cnt));
}

extern "C" void kernel_launch(void* const* d_in, const int* in_sizes, int n_in,
                              void* d_out, int out_size, void* d_ws, size_t ws_size,
                              hipStream_t stream) {
    const float* x = (const float*)d_in[0];
    const int* ei = (const int*)d_in[1];
    const int* src = ei;
    const int* dst = ei + NE;
    const int* batch = (const int*)d_in[2];
    const float* gc_W1 = (const float*)d_in[4];
    const float* gc_b1 = (const float*)d_in[5];
    const float* gc_W2 = (const float*)d_in[6];
    const float* gc_b2 = (const float*)d_in[7];
    const float* gc_g = (const float*)d_in[8];
    const float* gc_be = (const float*)d_in[9];
    const float* h0_W1 = (const float*)d_in[10];
    const float* h0_b1 = (const float*)d_in[11];
    const float* h0_W2 = (const float*)d_in[12];
    const float* h0_b2 = (const float*)d_in[13];
    const float* h0_g = (const float*)d_in[14];
    const float* h0_be = (const float*)d_in[15];
    const float* h1_W1 = (const float*)d_in[16];
    const float* h1_b1 = (const float*)d_in[17];
    const float* h1_W2 = (const float*)d_in[18];
    const float* h1_b2 = (const float*)d_in[19];
    const float* h1_g = (const float*)d_in[20];
    const float* h1_be = (const float*)d_in[21];

    const size_t NF = (size_t)NN * FF;
    float* P0 = (float*)d_ws;
    float* P1 = P0 + NF;
    float* P2 = P1 + NF;
    float* stats = P2 + NF;
    int* deg = (int*)(stats + 5 * 256);
    int* cnt = deg + NN;
    int* offs = cnt + NN;
    int* bsum = offs + (NN + 4);
    int* boffs = bsum + 256;
    int* csr = boffs + 256;

    hipMemsetAsync(deg, 0, (size_t)2 * NN * sizeof(int), stream);
    hipMemsetAsync(stats, 0, 5 * 256 * sizeof(float), stream);
    hipMemsetAsync(d_out, 0, (size_t)GG * KF * DD * sizeof(float), stream);

    k_deg<<<(NE + 255) / 256, 256, 0, stream>>>(dst, deg);
    k_bsum<<<NB, 256, 0, stream>>>(deg, bsum);
    k_bscan<<<1, 256, 0, stream>>>(bsum, boffs);
    k_offs<<<NB, 256, 0, stream>>>(deg, boffs, offs);
    k_fill<<<(NE + 255) / 256, 256, 0, stream>>>(src, dst, offs, cnt, csr);

    const int agg_grid = NN / 8;            // 6250
    const int gemm_grid = (NN + 63) / 64;   // 782

    // ---- GC layers: agg + fused gemm pair (stats fused) ----
    k_agg<false, false><<<agg_grid, 256, 0, stream>>>(
        (const float4*)x, offs, csr, nullptr, nullptr, nullptr, (float4*)P0);
    gemm_pair<<<gemm_grid, 256, 0, stream>>>(P0, gc_W1, gc_b1, gc_W2, gc_b2, P2, NN, stats);

    k_agg<true, true><<<agg_grid, 256, 0, stream>>>(
        (const float4*)P2, offs, csr, stats, gc_g, gc_be, (float4*)P0);
    gemm_pair<<<gemm_grid, 256, 0, stream>>>(P0, gc_W1 + FF * FF, gc_b1 + FF,
                                             gc_W2 + FF * FF, gc_b2 + FF, P2, NN, stats + 256);

    k_agg<true, true><<<agg_grid, 256, 0, stream>>>(
        (const float4*)P2, offs, csr, stats + 256, gc_g + FF, gc_be + FF, (float4*)P0);
    gemm_pair<<<gemm_grid, 256, 0, stream>>>(P0, gc_W1 + 2 * FF * FF, gc_b1 + 2 * FF,
                                             gc_W2 + 2 * FF * FF, gc_b2 + 2 * FF, P2, NN, stats + 512);

    // ---- head layer 0: agg (GC2 BN, no relu) + fused repack-gemm/bd/stats ----
    k_agg<true, false><<<agg_grid, 256, 0, stream>>>(
        (const float4*)P2, offs, csr, stats + 512, gc_g + 2 * FF, gc_be + 2 * FF, (float4*)P0);
    gemm_h0<<<gemm_grid, 256, 0, stream>>>(P0, h0_W1, h0_b1, h0_W2, h0_b2, P2, NN, stats + 768);

    // ---- head layer 1: fused agg(BN+relu) + double block-diag MLP ----
    k_aggbd<<<agg_grid, 256, 0, stream>>>(
        (const float4*)P2, offs, csr, stats + 768, h0_g, h0_be,
        h1_W1, (const float4*)h1_b1, h1_W2, (const float4*)h1_b2, (float4*)P1);
    k_stats<<<256, 256, 0, stream>>>(P1, stats + 1024, NN);

    // ---- pool with fused final BN ----
    k_pool<<<512, 128, 0, stream>>>(P1, batch, stats + 1024, h1_g, h1_be, (float*)d_out);
}